// Round 11
// baseline (128.797 us; speedup 1.0000x reference)
//
#include <hip/hip_runtime.h>
#include <hip/hip_bf16.h>

#define C_ 384
#define B_ 16
#define H_ 56
#define W_ 56
#define PAD_ 6
#define NPL_ 8               // planes per block
#define TPB_ 448             // 7 waves; 56 threads per plane (14 xg * 4 yg)
#define PLANE32_ 2312        // 68 rows * 34 u32 (f16 pairs) per plane
#define WROW_ 8              // u32 weight-pairs per ky row (7 used + pad)

typedef _Float16 half2v __attribute__((ext_vector_type(2)));

// ---- folded weight value for (c, py, px), px<13 ----
__device__ __forceinline__ float foldw(int c, int py, int px,
    const float* lk, const float* w5, const float* w7a, const float* w7b,
    const float* w3a, const float* w3b, const float* w3c, const float* sc)
{
    int dy = py - 6, dx = px - 6;
    float a = sc[0] * lk[c * 169 + py * 13 + px];
#define ADDBR(Wp, K, R, SI)                                               \
    {                                                                     \
        const int half = ((K) - 1) / 2;                                   \
        if (dy % (R) == 0 && dx % (R) == 0) {                             \
            int iy = dy / (R), ix = dx / (R);                             \
            if (iy >= -half && iy <= half && ix >= -half && ix <= half)   \
                a += sc[SI] * Wp[c * (K) * (K) + (iy + half) * (K) + (ix + half)]; \
        }                                                                 \
    }
    ADDBR(w5,  5, 1, 1)
    ADDBR(w7a, 7, 1, 2)
    ADDBR(w7b, 7, 2, 3)
    ADDBR(w3a, 3, 3, 4)
    ADDBR(w3b, 3, 4, 5)
    ADDBR(w3c, 3, 5, 6)
#undef ADDBR
    return a;
}

// Fold 7 branches (conv+BN) into one 13x13 kernel per channel, stored as
// f16 PAIRS for v_dot2: wpk[c][ky][p] = half2(w[2p], w[2p+1]), w[13..15]=0.
__global__ void build_weights_kernel(
    const float* __restrict__ lk, const float* __restrict__ obn,
    const float* __restrict__ w5, const float* __restrict__ w7a,
    const float* __restrict__ w7b, const float* __restrict__ w3a,
    const float* __restrict__ w3b, const float* __restrict__ w3c,
    const float* __restrict__ brbn,
    unsigned* __restrict__ wpk, float* __restrict__ bias)
{
    int c = blockIdx.x;
    int t = threadIdx.x;

    float sc[7], sh[7];
    {
        float g = obn[c], b = obn[C_ + c], m = obn[2 * C_ + c], v = obn[3 * C_ + c];
        float s = g * rsqrtf(v + 1e-5f);
        sc[0] = s; sh[0] = b - m * s;
    }
#pragma unroll
    for (int i = 0; i < 6; ++i) {
        float g = brbn[(i * 4 + 0) * C_ + c], b = brbn[(i * 4 + 1) * C_ + c];
        float m = brbn[(i * 4 + 2) * C_ + c], v = brbn[(i * 4 + 3) * C_ + c];
        float s = g * rsqrtf(v + 1e-5f);
        sc[i + 1] = s; sh[i + 1] = b - m * s;
    }

    if (t < 13 * WROW_) {
        int ky = t / WROW_, pp = t % WROW_;
        int kx0 = 2 * pp, kx1 = 2 * pp + 1;
        float w0 = (kx0 < 13) ? foldw(c, ky, kx0, lk, w5, w7a, w7b, w3a, w3b, w3c, sc) : 0.f;
        float w1 = (kx1 < 13) ? foldw(c, ky, kx1, lk, w5, w7a, w7b, w3a, w3b, w3c, sc) : 0.f;
        _Float16 h0 = (_Float16)w0, h1 = (_Float16)w1;
        unsigned u = ((unsigned)__builtin_bit_cast(unsigned short, h1) << 16)
                   |  (unsigned)__builtin_bit_cast(unsigned short, h0);
        wpk[c * 13 * WROW_ + t] = u;
    }
    if (t == 0) {
        float s = 0.f;
#pragma unroll
        for (int i = 0; i < 7; ++i) s += sh[i];
        bias[c] = s;
    }
}

// One block: 8 planes of channel c in LDS as f16 pairs (74KB -> 2 blocks/CU).
// Weights ALSO in LDS (104 u32, broadcast reads): all inner-loop memory ops
// are in-order DS -> counted lgkmcnt waits, NO smem-induced full drains.
// Per thread: 4-wide x 14-tall tile (amplification 26/14 = 1.86 vs 2.71).
__global__ __launch_bounds__(TPB_, 4) void dwconv13_kernel(
    const float* __restrict__ x, const unsigned* __restrict__ wpk,
    const float* __restrict__ bias, float* __restrict__ out)
{
    __shared__ unsigned swt[13 * WROW_];        // 416 B weights
    __shared__ unsigned sxu[NPL_ * PLANE32_];   // 73984 B data

    int bid = blockIdx.x;
    int c  = bid % C_;
    int bg = bid / C_;
    int t  = threadIdx.x;

    // ---- Weight copy (global->LDS, once per block). ----
    if (t < 13 * WROW_) swt[t] = wpk[c * 13 * WROW_ + t];

    // ---- Stage: 8 planes * 56 rows * 28 f16-pairs = 12544 u32 -> 28/thr. ----
    unsigned vvp[28]; int ddp[28];
#pragma unroll
    for (int k = 0; k < 28; ++k) {
        int slot = t + k * TPB_;
        int p    = slot / 1568;            // 1568 = 56*28
        int rem  = slot - p * 1568;
        int iy   = rem / 28;
        int pr   = rem - iy * 28;
        const float* xp = x + ((size_t)(bg * NPL_ + p) * C_ + c) * (H_ * W_);
        float2 v = *(const float2*)(xp + iy * W_ + pr * 2);
        _Float16 h0 = (_Float16)v.x, h1 = (_Float16)v.y;   // RNE converts
        vvp[k] = ((unsigned)__builtin_bit_cast(unsigned short, h1) << 16)
               |  (unsigned)__builtin_bit_cast(unsigned short, h0);
        ddp[k] = p * PLANE32_ + (iy + PAD_) * 34 + 3 + pr; // f16 col 6+2pr
    }

    // ---- Zero whole data LDS (halo = padding): 18496 u32 = 4624 uint4. ----
    {
        uint4 z = make_uint4(0u, 0u, 0u, 0u);
        uint4* s4 = (uint4*)sxu;
#pragma unroll
        for (int k = 0; k < 11; ++k) {
            int slot = t + k * TPB_;
            if (k < 10 || slot < 4624) s4[slot] = z;
        }
    }
    __syncthreads();

#pragma unroll
    for (int k = 0; k < 28; ++k) sxu[ddp[k]] = vvp[k];
    __syncthreads();

    float bv = bias[c];

    int p   = t / 56;
    int r   = t - p * 56;
    int yg  = r & 3;          // yg-major lane map
    int xg  = r >> 2;         // 0..13
    int x0 = xg * 4, y0 = yg * 14;
    const unsigned* sp32 = sxu + p * PLANE32_;

    float acc[14][4];
#pragma unroll
    for (int i = 0; i < 14; ++i)
#pragma unroll
        for (int j = 0; j < 4; ++j) acc[i][j] = bv;

    // Row window = 8 u32 (16 f16), pair-aligned: 4x ds_read_b64.
#define LOADROW(Eb, rr) {                                                  \
        const unsigned* rp_ = sp32 + (y0 + (rr)) * 34 + 2 * xg;            \
        *(uint2*)((Eb) + 0) = *(const uint2*)(rp_ + 0);                    \
        *(uint2*)((Eb) + 2) = *(const uint2*)(rp_ + 2);                    \
        *(uint2*)((Eb) + 4) = *(const uint2*)(rp_ + 4);                    \
        *(uint2*)((Eb) + 6) = *(const uint2*)(rp_ + 6);                    \
    }

    // Per row: odd-phase pairs via alignbit, then dot2 bursts; weights from
    // LDS (broadcast, in-order with data reads).
#define DOROW(Eb, rr) {                                                    \
        unsigned Ob[8];                                                    \
        _Pragma("unroll")                                                  \
        for (int q = 0; q < 7; ++q)                                        \
            Ob[q] = __builtin_amdgcn_alignbit((Eb)[q + 1], (Eb)[q], 16);   \
        Ob[7] = (Eb)[7] >> 16;                                             \
        _Pragma("unroll")                                                  \
        for (int tt = 0; tt < 14; ++tt) {                                  \
            int ky = (rr) - tt;                                            \
            if (ky >= 0 && ky <= 12) {   /* compile-time after unroll */   \
                const unsigned* wr_ = swt + ky * WROW_;                    \
                unsigned wv_[7];                                           \
                _Pragma("unroll")                                          \
                for (int p6 = 0; p6 < 7; ++p6) wv_[p6] = wr_[p6];          \
                _Pragma("unroll")                                          \
                for (int j = 0; j < 4; ++j) {                              \
                    int q0 = j >> 1;                                       \
                    _Pragma("unroll")                                      \
                    for (int p6 = 0; p6 < 7; ++p6) {                       \
                        unsigned iv = (j & 1) ? Ob[q0 + p6] : (Eb)[q0 + p6]; \
                        acc[tt][j] = __builtin_amdgcn_fdot2(               \
                            __builtin_bit_cast(half2v, iv),                \
                            __builtin_bit_cast(half2v, wv_[p6]),           \
                            acc[tt][j], false);                            \
                    }                                                      \
                }                                                          \
            }                                                              \
        }                                                                  \
    }

    // 2-deep double-buffered sliding window over the 26 padded input rows.
    unsigned E0[8], E1[8];
    LOADROW(E0, 0)
#pragma unroll
    for (int rb = 0; rb < 13; ++rb) {
        const int ra = 2 * rb;
        if (ra + 1 < 26) LOADROW(E1, ra + 1)
        DOROW(E0, ra)
        if (ra + 2 < 26) LOADROW(E0, ra + 2)
        if (ra + 1 < 26) DOROW(E1, ra + 1)
    }
#undef DOROW
#undef LOADROW

    float* op = out + ((size_t)(bg * NPL_ + p) * C_ + c) * (H_ * W_);
#pragma unroll
    for (int tt = 0; tt < 14; ++tt) {
        float4 v = make_float4(acc[tt][0], acc[tt][1], acc[tt][2], acc[tt][3]);
        *(float4*)(op + (y0 + tt) * W_ + x0) = v;
    }
}

extern "C" void kernel_launch(void* const* d_in, const int* in_sizes, int n_in,
                              void* d_out, int out_size, void* d_ws, size_t ws_size,
                              hipStream_t stream) {
    const float* x    = (const float*)d_in[0];
    const float* lk   = (const float*)d_in[1];
    const float* obn  = (const float*)d_in[2];
    const float* w5   = (const float*)d_in[3];
    const float* w7a  = (const float*)d_in[4];
    const float* w7b  = (const float*)d_in[5];
    const float* w3a  = (const float*)d_in[6];
    const float* w3b  = (const float*)d_in[7];
    const float* w3c  = (const float*)d_in[8];
    const float* brbn = (const float*)d_in[9];
    float* out  = (float*)d_out;

    unsigned* wpk = (unsigned*)d_ws;             // 384*104 u32 = 159744 B
    float*    bias = (float*)(wpk + C_ * 13 * WROW_);  // 384 floats

    hipLaunchKernelGGL(build_weights_kernel, dim3(C_), dim3(128), 0, stream,
                       lk, obn, w5, w7a, w7b, w3a, w3b, w3c, brbn, wpk, bias);

    hipLaunchKernelGGL(dwconv13_kernel, dim3((B_ / NPL_) * C_), dim3(TPB_), 0, stream,
                       x, wpk, bias, out);
}

// Round 12
// 94.602 us; speedup vs baseline: 1.3615x; 1.3615x over previous
//
#include <hip/hip_runtime.h>
#include <hip/hip_bf16.h>

#define C_ 384
#define B_ 16
#define H_ 56
#define W_ 56
#define PAD_ 6
#define NPL_ 4               // planes per block
#define TPB_ 448             // 7 waves; 112 threads per plane
#define PLANE32_ 2312        // 68 rows * 34 u32 (f16 pairs) per plane
#define WROW_ 8              // u32 weight-pairs per ky row (7 used + pad)

typedef _Float16 half2v __attribute__((ext_vector_type(2)));

// ---- folded weight value for (c, py, px), px<13 ----
__device__ __forceinline__ float foldw(int c, int py, int px,
    const float* lk, const float* w5, const float* w7a, const float* w7b,
    const float* w3a, const float* w3b, const float* w3c, const float* sc)
{
    int dy = py - 6, dx = px - 6;
    float a = sc[0] * lk[c * 169 + py * 13 + px];
#define ADDBR(Wp, K, R, SI)                                               \
    {                                                                     \
        const int half = ((K) - 1) / 2;                                   \
        if (dy % (R) == 0 && dx % (R) == 0) {                             \
            int iy = dy / (R), ix = dx / (R);                             \
            if (iy >= -half && iy <= half && ix >= -half && ix <= half)   \
                a += sc[SI] * Wp[c * (K) * (K) + (iy + half) * (K) + (ix + half)]; \
        }                                                                 \
    }
    ADDBR(w5,  5, 1, 1)
    ADDBR(w7a, 7, 1, 2)
    ADDBR(w7b, 7, 2, 3)
    ADDBR(w3a, 3, 3, 4)
    ADDBR(w3b, 3, 4, 5)
    ADDBR(w3c, 3, 5, 6)
#undef ADDBR
    return a;
}

// Fold 7 branches (conv+BN) into one 13x13 kernel per channel, stored as
// f16 PAIRS for v_dot2: wpk[c][ky][p] = half2(w[2p], w[2p+1]), w[13..15]=0.
__global__ void build_weights_kernel(
    const float* __restrict__ lk, const float* __restrict__ obn,
    const float* __restrict__ w5, const float* __restrict__ w7a,
    const float* __restrict__ w7b, const float* __restrict__ w3a,
    const float* __restrict__ w3b, const float* __restrict__ w3c,
    const float* __restrict__ brbn,
    unsigned* __restrict__ wpk, float* __restrict__ bias)
{
    int c = blockIdx.x;
    int t = threadIdx.x;

    float sc[7], sh[7];
    {
        float g = obn[c], b = obn[C_ + c], m = obn[2 * C_ + c], v = obn[3 * C_ + c];
        float s = g * rsqrtf(v + 1e-5f);
        sc[0] = s; sh[0] = b - m * s;
    }
#pragma unroll
    for (int i = 0; i < 6; ++i) {
        float g = brbn[(i * 4 + 0) * C_ + c], b = brbn[(i * 4 + 1) * C_ + c];
        float m = brbn[(i * 4 + 2) * C_ + c], v = brbn[(i * 4 + 3) * C_ + c];
        float s = g * rsqrtf(v + 1e-5f);
        sc[i + 1] = s; sh[i + 1] = b - m * s;
    }

    if (t < 13 * WROW_) {
        int ky = t / WROW_, pp = t % WROW_;
        int kx0 = 2 * pp, kx1 = 2 * pp + 1;
        float w0 = (kx0 < 13) ? foldw(c, ky, kx0, lk, w5, w7a, w7b, w3a, w3b, w3c, sc) : 0.f;
        float w1 = (kx1 < 13) ? foldw(c, ky, kx1, lk, w5, w7a, w7b, w3a, w3b, w3c, sc) : 0.f;
        _Float16 h0 = (_Float16)w0, h1 = (_Float16)w1;
        unsigned u = ((unsigned)__builtin_bit_cast(unsigned short, h1) << 16)
                   |  (unsigned)__builtin_bit_cast(unsigned short, h0);
        wpk[c * 13 * WROW_ + t] = u;
    }
    if (t == 0) {
        float s = 0.f;
#pragma unroll
        for (int i = 0; i < 7; ++i) s += sh[i];
        bias[c] = s;
    }
}

// One block: 4 planes of channel c in LDS as f16 pairs (37KB). All 91 weight
// pairs preloaded into VGPRs (uniform loads at kernel top, latency hidden
// under staging): the inner loop's ONLY memory ops are the 4 data ds_read
// per row -> in-order lgkm, compiler's counted partial waits, no SMEM drains.
__global__ __launch_bounds__(TPB_) void dwconv13_kernel(
    const float* __restrict__ x, const unsigned* __restrict__ wpk,
    const float* __restrict__ bias, float* __restrict__ out)
{
    __shared__ unsigned sxu[NPL_ * PLANE32_];   // 36992 B

    int bid = blockIdx.x;
    int c  = bid % C_;
    int bg = bid / C_;
    int t  = threadIdx.x;

    // ---- Weight preload into registers (91 u32 = f16 pairs). ----
    unsigned wreg[91];
#pragma unroll
    for (int ky = 0; ky < 13; ++ky) {
        const unsigned* wr = wpk + c * (13 * WROW_) + ky * WROW_;
        uint4 a = *(const uint4*)(wr);
        uint2 b2 = *(const uint2*)(wr + 4);
        unsigned e = wr[6];
        wreg[ky * 7 + 0] = a.x; wreg[ky * 7 + 1] = a.y;
        wreg[ky * 7 + 2] = a.z; wreg[ky * 7 + 3] = a.w;
        wreg[ky * 7 + 4] = b2.x; wreg[ky * 7 + 5] = b2.y;
        wreg[ky * 7 + 6] = e;
    }
    float bv = bias[c];

    // ---- Stage: 4*56 rows * 28 f16-pairs = 6272 u32 -> 14 per thread. ----
    unsigned vvp[14]; int ddp[14];
#pragma unroll
    for (int k = 0; k < 14; ++k) {
        int slot = t + k * TPB_;
        int p    = slot / 1568;            // 1568 = 56*28
        int rem  = slot - p * 1568;
        int iy   = rem / 28;
        int pr   = rem - iy * 28;
        const float* xp = x + ((size_t)(bg * NPL_ + p) * C_ + c) * (H_ * W_);
        float2 v = *(const float2*)(xp + iy * W_ + pr * 2);
        _Float16 h0 = (_Float16)v.x, h1 = (_Float16)v.y;   // RNE converts
        vvp[k] = ((unsigned)__builtin_bit_cast(unsigned short, h1) << 16)
               |  (unsigned)__builtin_bit_cast(unsigned short, h0);
        ddp[k] = p * PLANE32_ + (iy + PAD_) * 34 + 3 + pr; // f16 col 6+2pr
    }

    // ---- Zero whole LDS (halo = padding): 9248 u32 = 2312 uint4. ----
    {
        uint4 z = make_uint4(0u, 0u, 0u, 0u);
        uint4* s4 = (uint4*)sxu;
#pragma unroll
        for (int k = 0; k < 6; ++k) {
            int slot = t + k * TPB_;
            if (k < 5 || slot < 2312) s4[slot] = z;
        }
    }
    __syncthreads();

#pragma unroll
    for (int k = 0; k < 14; ++k) sxu[ddp[k]] = vvp[k];
    __syncthreads();

    int p   = t / 112;
    int r   = t - p * 112;
    int yg  = r & 7;          // yg-major lane map (R6's win)
    int xg  = r >> 3;
    int x0 = xg * 4, y0 = yg * 7;
    const unsigned* sp32 = sxu + p * PLANE32_;

    float acc[7][4];
#pragma unroll
    for (int i = 0; i < 7; ++i)
#pragma unroll
        for (int j = 0; j < 4; ++j) acc[i][j] = bv;

    // Row window = 8 u32 (16 f16), pair-aligned: 4x ds_read_b64.
#define LOADROW(Eb, rr) {                                                  \
        const unsigned* rp_ = sp32 + (y0 + (rr)) * 34 + 2 * xg;            \
        *(uint2*)((Eb) + 0) = *(const uint2*)(rp_ + 0);                    \
        *(uint2*)((Eb) + 2) = *(const uint2*)(rp_ + 2);                    \
        *(uint2*)((Eb) + 4) = *(const uint2*)(rp_ + 4);                    \
        *(uint2*)((Eb) + 6) = *(const uint2*)(rp_ + 6);                    \
    }

    // Per row: odd-phase pairs via alignbit, then dot2 bursts; weights come
    // from REGISTERS (compile-time indices) - zero memory ops here.
#define DOROW(Eb, rr) {                                                    \
        unsigned Ob[8];                                                    \
        _Pragma("unroll")                                                  \
        for (int q = 0; q < 7; ++q)                                        \
            Ob[q] = __builtin_amdgcn_alignbit((Eb)[q + 1], (Eb)[q], 16);   \
        Ob[7] = (Eb)[7] >> 16;                                             \
        _Pragma("unroll")                                                  \
        for (int tt = 0; tt < 7; ++tt) {                                   \
            int ky = (rr) - tt;                                            \
            if (ky >= 0 && ky <= 12) {   /* compile-time after unroll */   \
                const int wb = ky * 7;                                     \
                _Pragma("unroll")                                          \
                for (int j = 0; j < 4; ++j) {                              \
                    int q0 = j >> 1;                                       \
                    _Pragma("unroll")                                      \
                    for (int p6 = 0; p6 < 7; ++p6) {                       \
                        unsigned iv = (j & 1) ? Ob[q0 + p6] : (Eb)[q0 + p6]; \
                        acc[tt][j] = __builtin_amdgcn_fdot2(               \
                            __builtin_bit_cast(half2v, iv),                \
                            __builtin_bit_cast(half2v, wreg[wb + p6]),     \
                            acc[tt][j], false);                            \
                    }                                                      \
                }                                                          \
            }                                                              \
        }                                                                  \
    }

    // 2-deep double-buffered sliding window over the 19 padded input rows.
    unsigned E0[8], E1[8];
    LOADROW(E0, 0)
#pragma unroll
    for (int rb = 0; rb < 10; ++rb) {
        const int ra = 2 * rb;
        if (ra + 1 < 19) LOADROW(E1, ra + 1)
        DOROW(E0, ra)
        if (ra + 2 < 19) LOADROW(E0, ra + 2)
        if (ra + 1 < 19) DOROW(E1, ra + 1)
    }
#undef DOROW
#undef LOADROW

    float* op = out + ((size_t)(bg * NPL_ + p) * C_ + c) * (H_ * W_);
#pragma unroll
    for (int tt = 0; tt < 7; ++tt) {
        float4 v = make_float4(acc[tt][0], acc[tt][1], acc[tt][2], acc[tt][3]);
        *(float4*)(op + (y0 + tt) * W_ + x0) = v;
    }
}

extern "C" void kernel_launch(void* const* d_in, const int* in_sizes, int n_in,
                              void* d_out, int out_size, void* d_ws, size_t ws_size,
                              hipStream_t stream) {
    const float* x    = (const float*)d_in[0];
    const float* lk   = (const float*)d_in[1];
    const float* obn  = (const float*)d_in[2];
    const float* w5   = (const float*)d_in[3];
    const float* w7a  = (const float*)d_in[4];
    const float* w7b  = (const float*)d_in[5];
    const float* w3a  = (const float*)d_in[6];
    const float* w3b  = (const float*)d_in[7];
    const float* w3c  = (const float*)d_in[8];
    const float* brbn = (const float*)d_in[9];
    float* out  = (float*)d_out;

    unsigned* wpk = (unsigned*)d_ws;             // 384*104 u32 = 159744 B
    float*    bias = (float*)(wpk + C_ * 13 * WROW_);  // 384 floats

    hipLaunchKernelGGL(build_weights_kernel, dim3(C_), dim3(128), 0, stream,
                       lk, obn, w5, w7a, w7b, w3a, w3b, w3c, brbn, wpk, bias);

    hipLaunchKernelGGL(dwconv13_kernel, dim3((B_ / NPL_) * C_), dim3(TPB_), 0, stream,
                       x, wpk, bias, out);
}

// Round 14
// 44.952 us; speedup vs baseline: 2.8652x; 2.1045x over previous
//
#include <hip/hip_runtime.h>
#include <hip/hip_bf16.h>

#define C_ 384
#define B_ 16
#define H_ 56
#define W_ 56
#define WROW_ 8              // u32 weight-pairs per ky row in wpk
#define SPSZ_ 4944           // 2*2448 + 48 pad u32 (keeps all A-reads in-bounds)

typedef _Float16 f16x8 __attribute__((ext_vector_type(8)));
typedef float    f32x4 __attribute__((ext_vector_type(4)));

// ---- folded weight value for (c, py, px), px<13 ----
__device__ __forceinline__ float foldw(int c, int py, int px,
    const float* lk, const float* w5, const float* w7a, const float* w7b,
    const float* w3a, const float* w3b, const float* w3c, const float* sc)
{
    int dy = py - 6, dx = px - 6;
    float a = sc[0] * lk[c * 169 + py * 13 + px];
#define ADDBR(Wp, K, R, SI)                                               \
    {                                                                     \
        const int half = ((K) - 1) / 2;                                   \
        if (dy % (R) == 0 && dx % (R) == 0) {                             \
            int iy = dy / (R), ix = dx / (R);                             \
            if (iy >= -half && iy <= half && ix >= -half && ix <= half)   \
                a += sc[SI] * Wp[c * (K) * (K) + (iy + half) * (K) + (ix + half)]; \
        }                                                                 \
    }
    ADDBR(w5,  5, 1, 1)
    ADDBR(w7a, 7, 1, 2)
    ADDBR(w7b, 7, 2, 3)
    ADDBR(w3a, 3, 3, 4)
    ADDBR(w3b, 3, 4, 5)
    ADDBR(w3c, 3, 5, 6)
#undef ADDBR
    return a;
}

// wpk[c][ky][8 u32] = f16 pairs (w0..w12, 0,0,0); bias[c] = summed BN shifts.
__global__ void build_weights_kernel(
    const float* __restrict__ lk, const float* __restrict__ obn,
    const float* __restrict__ w5, const float* __restrict__ w7a,
    const float* __restrict__ w7b, const float* __restrict__ w3a,
    const float* __restrict__ w3b, const float* __restrict__ w3c,
    const float* __restrict__ brbn,
    unsigned* __restrict__ wpk, float* __restrict__ bias)
{
    int c = blockIdx.x;
    int t = threadIdx.x;

    float sc[7], sh[7];
    {
        float g = obn[c], b = obn[C_ + c], m = obn[2 * C_ + c], v = obn[3 * C_ + c];
        float s = g * rsqrtf(v + 1e-5f);
        sc[0] = s; sh[0] = b - m * s;
    }
#pragma unroll
    for (int i = 0; i < 6; ++i) {
        float g = brbn[(i * 4 + 0) * C_ + c], b = brbn[(i * 4 + 1) * C_ + c];
        float m = brbn[(i * 4 + 2) * C_ + c], v = brbn[(i * 4 + 3) * C_ + c];
        float s = g * rsqrtf(v + 1e-5f);
        sc[i + 1] = s; sh[i + 1] = b - m * s;
    }

    if (t < 13 * WROW_) {
        int ky = t / WROW_, pp = t % WROW_;
        int kx0 = 2 * pp, kx1 = 2 * pp + 1;
        float w0 = (kx0 < 13) ? foldw(c, ky, kx0, lk, w5, w7a, w7b, w3a, w3b, w3c, sc) : 0.f;
        float w1 = (kx1 < 13) ? foldw(c, ky, kx1, lk, w5, w7a, w7b, w3a, w3b, w3c, sc) : 0.f;
        _Float16 h0 = (_Float16)w0, h1 = (_Float16)w1;
        unsigned u = ((unsigned)__builtin_bit_cast(unsigned short, h1) << 16)
                   |  (unsigned)__builtin_bit_cast(unsigned short, h0);
        wpk[c * 13 * WROW_ + t] = u;
    }
    if (t == 0) {
        float s = 0.f;
#pragma unroll
        for (int i = 0; i < 7; ++i) s += sh[i];
        bias[c] = s;
    }
}

// MFMA depthwise conv. Block = 2 planes (batches 2bg, 2bg+1) of channel c.
// Per ky: OUT[16x16] += A[m][k] * B_ky[k][n]; A = input rows (M = 2 planes x
// 8 rows, exact 7x8=56 cover), B_ky = banded Toeplitz of weight row ky
// (B[k][n] = w[ky][k-n], zero outside band; K=32 covers the needed cols).
// k-slot-permutation-safe: A and B frags use the same logical k per slot.
__global__ __launch_bounds__(256) void dwconv13_mfma(
    const float* __restrict__ x, const unsigned* __restrict__ wpk,
    const float* __restrict__ bias, float* __restrict__ out)
{
    __shared__ unsigned sP[SPSZ_];      // 2 planes, 68 rows x 36 u32 + pad
    __shared__ unsigned sQ[13 * 24];    // padded weight rows: P[i]=w[i-16]
    __shared__ unsigned sB[13 * 256];   // B frags: [ky][lane][4 u32]

    const int bid = blockIdx.x;
    const int c   = bid % C_;
    const int bg  = bid / C_;     // 0..7
    const int b0  = bg * 2;
    const int t   = threadIdx.x;

    // ---- Phase 0: issue global loads; fill sQ (ALL 312 slots); zero sP. ----
    unsigned vv[13]; int dd[13];
#pragma unroll
    for (int k = 0; k < 13; ++k) {
        int slot = t + k * 256;
        if (k < 12 || slot < 3136) {
            int p  = slot / 1568, rem = slot - p * 1568;
            int iy = rem / 28,    pr  = rem - iy * 28;
            const float* xp = x + ((size_t)((b0 + p) * C_ + c)) * (H_ * W_);
            float2 v = *(const float2*)(xp + iy * W_ + pr * 2);
            _Float16 h0 = (_Float16)v.x, h1 = (_Float16)v.y;   // RNE
            vv[k] = ((unsigned)__builtin_bit_cast(unsigned short, h1) << 16)
                  |  (unsigned)__builtin_bit_cast(unsigned short, h0);
            dd[k] = p * 2448 + (iy + 6) * 36 + 3 + pr;
        }
    }
#pragma unroll
    for (int k = 0; k < 2; ++k) {      // R12 BUG FIX: covers all 312 entries
        int s = t + k * 256;
        if (s < 13 * 24) {
            int ky = s / 24, t24 = s - ky * 24;
            unsigned q = 0;
            if (t24 >= 8 && t24 < 16) q = wpk[c * 104 + ky * 8 + (t24 - 8)];
            sQ[s] = q;
        }
    }
    {
        uint4 z = make_uint4(0u, 0u, 0u, 0u);
        uint4* s4 = (uint4*)sP;
#pragma unroll
        for (int k = 0; k < 5; ++k) {
            int slot = t + k * 256;
            if (k < 4 || slot < SPSZ_ / 4) s4[slot] = z;
        }
    }
    __syncthreads();

    // ---- Phase 1: commit staged rows; build B fragments. ----
#pragma unroll
    for (int k = 0; k < 13; ++k) {
        int slot = t + k * 256;
        if (k < 12 || slot < 3136) sP[dd[k]] = vv[k];
    }
#pragma unroll
    for (int k = 0; k < 13; ++k) {
        int e   = t + k * 256;            // 13*256 = 3328 exact
        int ky  = e >> 8, rem = e & 255;
        int ln  = rem >> 2, j = rem & 3;
        int g   = ln >> 4,  n = ln & 15;
        int q   = 16 + 8 * g + 2 * j - n;     // f16 pair start in padded row
        const unsigned* Q = sQ + ky * 24;
        unsigned v = (n & 1) ? ((Q[(q - 1) >> 1] >> 16) | (Q[(q + 1) >> 1] << 16))
                             : Q[q >> 1];
        sB[e] = v;
    }
    __syncthreads();

    // ---- Phase 2: compute. Wave w owns col-tile x0 = 16w, loops 7 row-tiles.
    const float bv  = bias[c];
    const int lane = t & 63;
    const int wv   = t >> 6;          // 0..3
    const int x0   = wv * 16;
    const int g    = lane >> 4, n = lane & 15;
    const int r8   = lane & 7,  pp = (lane >> 3) & 1;

    f16x8 bf[13];
#pragma unroll
    for (int ky = 0; ky < 13; ++ky) {
        uint4 u = *(const uint4*)(sB + ky * 256 + lane * 4);
        bf[ky] = __builtin_bit_cast(f16x8, u);
    }

    const int aBase = pp * 2448 + r8 * 36 + x0 / 2 + 4 * g;
    const int xo = x0 + n;

#pragma unroll
    for (int ty = 0; ty < 7; ++ty) {
        f32x4 d0 = { bv, bv, bv, bv };
        f32x4 d1 = { 0.f, 0.f, 0.f, 0.f };
        int base = aBase + (8 * ty) * 36;
        uint4 ua = *(const uint4*)(sP + base);
#pragma unroll
        for (int ky = 0; ky < 13; ++ky) {
            uint4 un;
            if (ky < 12) un = *(const uint4*)(sP + base + (ky + 1) * 36);
            f16x8 a = __builtin_bit_cast(f16x8, ua);
            if (ky & 1) d1 = __builtin_amdgcn_mfma_f32_16x16x32_f16(a, bf[ky], d1, 0, 0, 0);
            else        d0 = __builtin_amdgcn_mfma_f32_16x16x32_f16(a, bf[ky], d0, 0, 0, 0);
            if (ky < 12) ua = un;
        }
        d0 = d0 + d1;
        if (xo < W_) {
#pragma unroll
            for (int r = 0; r < 4; ++r) {
                int m  = 4 * g + r;           // D row = M index
                int p2 = m >> 3, rr = m & 7;
                out[((size_t)((b0 + p2) * C_ + c)) * (H_ * W_)
                    + (8 * ty + rr) * W_ + xo] = d0[r];
            }
        }
    }
}

extern "C" void kernel_launch(void* const* d_in, const int* in_sizes, int n_in,
                              void* d_out, int out_size, void* d_ws, size_t ws_size,
                              hipStream_t stream) {
    const float* x    = (const float*)d_in[0];
    const float* lk   = (const float*)d_in[1];
    const float* obn  = (const float*)d_in[2];
    const float* w5   = (const float*)d_in[3];
    const float* w7a  = (const float*)d_in[4];
    const float* w7b  = (const float*)d_in[5];
    const float* w3a  = (const float*)d_in[6];
    const float* w3b  = (const float*)d_in[7];
    const float* w3c  = (const float*)d_in[8];
    const float* brbn = (const float*)d_in[9];
    float* out  = (float*)d_out;

    unsigned* wpk  = (unsigned*)d_ws;                  // 384*104 u32
    float*    bias = (float*)(wpk + C_ * 13 * WROW_);  // 384 floats

    hipLaunchKernelGGL(build_weights_kernel, dim3(C_), dim3(128), 0, stream,
                       lk, obn, w5, w7a, w7b, w3a, w3b, w3c, brbn, wpk, bias);

    hipLaunchKernelGGL(dwconv13_mfma, dim3((B_ / 2) * C_), dim3(256), 0, stream,
                       x, wpk, bias, out);
}